// Round 1
// baseline (144.439 us; speedup 1.0000x reference)
//
#include <hip/hip_runtime.h>
#include <hip/hip_bf16.h>

typedef __attribute__((ext_vector_type(8))) short bf16x8;
typedef __attribute__((ext_vector_type(4))) float f32x4;

#define NB 32
#define NS 512
#define ND 1024

__device__ __forceinline__ unsigned short f2bf(float f) {
  unsigned int u = __float_as_uint(f);
  u = (u + 0x7FFFu + ((u >> 16) & 1u)) >> 16;  // RNE
  return (unsigned short)u;
}

// ---------- normalized aspect -> bf16 ----------
__global__ void anorm_kernel(const float* __restrict__ aspect,
                             unsigned short* __restrict__ a_n) {
  int b = blockIdx.x;
  int t = threadIdx.x;
  const float4* p = (const float4*)(aspect + (size_t)b * ND);
  float4 v = p[t];
  float s = v.x * v.x + v.y * v.y + v.z * v.z + v.w * v.w;
#pragma unroll
  for (int off = 32; off >= 1; off >>= 1) s += __shfl_down(s, off);
  __shared__ float red[4];
  if ((t & 63) == 0) red[t >> 6] = s;
  __syncthreads();
  float tot = red[0] + red[1] + red[2] + red[3];
  float inv = (tot > 0.f) ? (1.f / sqrtf(tot)) : 0.f;
  ushort4 u;
  u.x = f2bf(v.x * inv); u.y = f2bf(v.y * inv);
  u.z = f2bf(v.z * inv); u.w = f2bf(v.w * inv);
  ((ushort4*)(a_n + (size_t)b * ND))[t] = u;
}

// ---------- precompute normalized embeddings as bf16 (one wave/row) ----------
__global__ __launch_bounds__(256)
void enormbf_kernel(const float* __restrict__ emb,
                    unsigned short* __restrict__ eN) {
  int wave = threadIdx.x >> 6, lane = threadIdx.x & 63;
  size_t row = (size_t)blockIdx.x * 4 + wave;  // 0..16383
  const float4* p = (const float4*)(emb + row * ND);
  float4 v[4];
  float s = 0.f;
#pragma unroll
  for (int j = 0; j < 4; ++j) {
    v[j] = p[lane + 64 * j];
    s += v[j].x * v[j].x + v[j].y * v[j].y + v[j].z * v[j].z + v[j].w * v[j].w;
  }
#pragma unroll
  for (int off = 32; off >= 1; off >>= 1) s += __shfl_xor(s, off);
  float inv = (s > 0.f) ? (1.f / sqrtf(s)) : 0.f;
  ushort4* o = (ushort4*)(eN + row * ND);
#pragma unroll
  for (int j = 0; j < 4; ++j) {
    ushort4 u;
    u.x = f2bf(v[j].x * inv); u.y = f2bf(v[j].y * inv);
    u.z = f2bf(v[j].z * inv); u.w = f2bf(v[j].w * inv);
    o[lane + 64 * j] = u;
  }
}

// ---------- GEMM v4: 256x256 tile, 8 waves, 8-phase schedule, ring-3 A-dbuf,
// counted vmcnt (never 0 mid-loop), setprio around MFMA clusters ----------
// LDS: A ring 3 x (256x64 bf16) = 96 KiB; circulant copies 8 x 1288 = 20.1 KiB.
// copies[p][x] = a[(x + 768 - n0 + p) & 1023]; B frag at idx = k + 256 - n,
// p = idx & 7 = (-l16) & 7 (per-lane constant), addr = copies + p*1287 + idx.
// A swizzle: slot s holds chunk s ^ (m & 7) (linear LDS dst, inverse-swz src).
__global__ __launch_bounds__(512, 2)
void corr_gemm4_kernel(const unsigned short* __restrict__ eN,
                       const unsigned short* __restrict__ a_n,
                       float* __restrict__ out) {
  __shared__ __align__(16) unsigned short Alds[3 * 16384];   // 3 x 256 x 64
  __shared__ __align__(16) unsigned short copies[8 * 1288];

  const int b = blockIdx.x, mt = blockIdx.y, nt = blockIdx.z;
  const int n0 = nt * 256, m0 = mt * 256;
  const int tid = threadIdx.x;

  // ---- stage circulant copies (once per block): 8 x 1280 entries ----
  {
    const unsigned short* an = a_n + (size_t)b * ND;
    const int p = tid & 7;
    const int x0 = (tid >> 3) * 20;                 // 64 threads/copy x 20 = 1280
    const int base = (768 - n0 + p) & 1023;
#pragma unroll
    for (int j = 0; j < 20; j += 4) {
      ushort4 u;
      u.x = an[(base + x0 + j + 0) & 1023];
      u.y = an[(base + x0 + j + 1) & 1023];
      u.z = an[(base + x0 + j + 2) & 1023];
      u.w = an[(base + x0 + j + 3) & 1023];
      *(ushort4*)&copies[p * 1288 + x0 + j] = u;
    }
  }

  const int lane = tid & 63, wv = tid >> 6;
  const int wm = wv >> 2, wn = wv & 3;      // 2x4 waves over 256x256 (128x64 each)
  const int q = lane >> 4, l16 = lane & 15;
  const int mx = l16 & 7;
  const int s00 = (q ^ mx) * 8;             // chunk q       (kk=0)
  const int s01 = ((4 + q) ^ mx) * 8;       // chunk 4+q     (kk=1)
  const int arow = (wm * 128 + l16) * 64;

  // B read base: addr = copies + pB*1287 + idx ; idx = kt*64 + kk*32 + 8q + 256 - n_local
  const int pB = (8 - mx) & 7;
  const unsigned short* Bp = copies + pB * 1287 + (256 + 8 * q - wn * 64 - l16);

  // A staging source (inverse chunk swizzle), linear LDS dst = tid*16 per issue block
  const unsigned short* gstage =
      eN + ((size_t)b * NS + m0 + (tid >> 3)) * ND + (size_t)(((tid & 7) ^ ((tid >> 3) & 7)) * 8);
  char* ldsAbase = (char*)Alds;

  f32x4 acc[8][4];
#pragma unroll
  for (int i = 0; i < 8; ++i)
#pragma unroll
    for (int j = 0; j < 4; ++j)
      acc[i][j] = (f32x4){0.f, 0.f, 0.f, 0.f};

  // ---- prologue: copies visible + clean vmcnt, then stage tiles 0 and 1 ----
  __syncthreads();
#pragma unroll
  for (int j = 0; j < 4; ++j)
    __builtin_amdgcn_global_load_lds(
        (const __attribute__((address_space(1))) void*)(gstage + (size_t)j * 64 * ND),
        (__attribute__((address_space(3))) void*)(ldsAbase + (size_t)tid * 16 + j * 8192),
        16, 0, 0);
#pragma unroll
  for (int j = 0; j < 4; ++j)
    __builtin_amdgcn_global_load_lds(
        (const __attribute__((address_space(1))) void*)(gstage + (size_t)j * 64 * ND + 64),
        (__attribute__((address_space(3))) void*)(ldsAbase + 32768 + (size_t)tid * 16 + j * 8192),
        16, 0, 0);
  asm volatile("s_waitcnt vmcnt(4)" ::: "memory");   // tile0 retired; tile1 in flight
  __builtin_amdgcn_sched_barrier(0);
  __builtin_amdgcn_s_barrier();

  int c0 = 0, c1 = 1, c2 = 2;  // ring: read c0, (tile+1) in c1, stage (tile+2) -> c2

#define STAGE_PAIR(J0)                                                                   \
  do {                                                                                   \
    if (kt + 2 < 16) {                                                                   \
      const unsigned short* sg_ = gstage + (size_t)(kt + 2) * 64;                        \
      char* dl_ = ldsAbase + c2 * 32768 + (size_t)tid * 16;                              \
      __builtin_amdgcn_global_load_lds(                                                  \
          (const __attribute__((address_space(1))) void*)(sg_ + (size_t)(J0) * 64 * ND), \
          (__attribute__((address_space(3))) void*)(dl_ + (J0) * 8192), 16, 0, 0);       \
      __builtin_amdgcn_global_load_lds(                                                  \
          (const __attribute__((address_space(1))) void*)(sg_ + (size_t)((J0) + 1) * 64 * ND), \
          (__attribute__((address_space(3))) void*)(dl_ + ((J0) + 1) * 8192), 16, 0, 0); \
    }                                                                                    \
  } while (0)

#define GEMM_PHASE(PH, EXTRA)                                                            \
  do {                                                                                   \
    bf16x8 aA0  = *(const bf16x8*)&At[arow + (PH)*2048 + s00];                           \
    bf16x8 aA0k = *(const bf16x8*)&At[arow + (PH)*2048 + s01];                           \
    bf16x8 aA1  = *(const bf16x8*)&At[arow + (PH)*2048 + 1024 + s00];                    \
    bf16x8 aA1k = *(const bf16x8*)&At[arow + (PH)*2048 + 1024 + s01];                    \
    EXTRA;                                                                               \
    __builtin_amdgcn_s_barrier();                                                        \
    asm volatile("s_waitcnt lgkmcnt(0)" ::: "memory");                                   \
    __builtin_amdgcn_sched_barrier(0);                                                   \
    __builtin_amdgcn_s_setprio(1);                                                       \
    _Pragma("unroll")                                                                    \
    for (int n = 0; n < 4; ++n) {                                                        \
      acc[2*(PH)][n]   = __builtin_amdgcn_mfma_f32_16x16x32_bf16(aA0,  bfr[n][0], acc[2*(PH)][n],   0, 0, 0); \
      acc[2*(PH)][n]   = __builtin_amdgcn_mfma_f32_16x16x32_bf16(aA0k, bfr[n][1], acc[2*(PH)][n],   0, 0, 0); \
      acc[2*(PH)+1][n] = __builtin_amdgcn_mfma_f32_16x16x32_bf16(aA1,  bfr[n][0], acc[2*(PH)+1][n], 0, 0, 0); \
      acc[2*(PH)+1][n] = __builtin_amdgcn_mfma_f32_16x16x32_bf16(aA1k, bfr[n][1], acc[2*(PH)+1][n], 0, 0, 0); \
    }                                                                                    \
    __builtin_amdgcn_s_setprio(0);                                                       \
  } while (0)

#pragma unroll 1
  for (int kt = 0; kt < 16; ++kt) {
    const unsigned short* At = Alds + c0 * 16384;

    // ---- phase 0: all B frags for this K-tile + A rows 0-31, stage pair 0 ----
    bf16x8 bfr[4][2];
    {
      const unsigned short* Bt = Bp + kt * 64;
#pragma unroll
      for (int n = 0; n < 4; ++n) {
        bfr[n][0] = *(const bf16x8*)(Bt - n * 16);
        bfr[n][1] = *(const bf16x8*)(Bt + 32 - n * 16);
      }
    }
    GEMM_PHASE(0, STAGE_PAIR(0));
    __builtin_amdgcn_s_barrier();
    // ---- phase 1: A rows 32-63, stage pair 2 ----
    GEMM_PHASE(1, STAGE_PAIR(2));
    __builtin_amdgcn_s_barrier();
    // ---- phase 2: A rows 64-95 ----
    GEMM_PHASE(2, );
    __builtin_amdgcn_s_barrier();
    // ---- phase 3: A rows 96-127, then counted wait for next tile ----
    GEMM_PHASE(3, );
    if (kt < 14) {
      asm volatile("s_waitcnt vmcnt(4)" ::: "memory");  // tile kt+1 retired; kt+2 in flight
    } else if (kt == 14) {
      asm volatile("s_waitcnt vmcnt(0)" ::: "memory");  // tail: drain tile 15
    }
    __builtin_amdgcn_sched_barrier(0);
    __builtin_amdgcn_s_barrier();

    int tmp = c0; c0 = c1; c1 = c2; c2 = tmp;
  }
#undef GEMM_PHASE
#undef STAGE_PAIR

  // epilogue: C/D layout col=lane&15, row=(lane>>4)*4+reg
  float* outB = out + ((size_t)b * NS + m0) * ND + n0;
#pragma unroll
  for (int i = 0; i < 8; ++i) {
#pragma unroll
    for (int rg = 0; rg < 4; ++rg) {
      int r = wm * 128 + i * 16 + q * 4 + rg;
      float* orow = outB + (size_t)r * ND + wn * 64 + l16;
#pragma unroll
      for (int n = 0; n < 4; ++n)
        orow[n * 16] = acc[i][n][rg];
    }
  }
}

// ---------- fallback path (round-1 kernels) in case ws is small ----------
__global__ void enorm_kernel(const float* __restrict__ emb,
                             float* __restrict__ inv_norm) {
  int wave = threadIdx.x >> 6;
  int lane = threadIdx.x & 63;
  int row = blockIdx.x * 4 + wave;
  const float4* p = (const float4*)(emb + (size_t)row * ND);
  float s = 0.f;
#pragma unroll
  for (int j = 0; j < 4; ++j) {
    float4 v = p[lane + 64 * j];
    s += v.x * v.x + v.y * v.y + v.z * v.z + v.w * v.w;
  }
#pragma unroll
  for (int off = 32; off >= 1; off >>= 1) s += __shfl_down(s, off);
  if (lane == 0) inv_norm[row] = (s > 0.f) ? (1.f / sqrtf(s)) : 0.f;
}

__global__ __launch_bounds__(256)
void corr_gemm_kernel(const float* __restrict__ emb,
                      const float* __restrict__ inv_norm,
                      const unsigned short* __restrict__ a_n,
                      float* __restrict__ out) {
  __shared__ unsigned short copies[8][2056];
  __shared__ unsigned short Atile[128][40];

  const int nt = blockIdx.x, mt = blockIdx.y, b = blockIdx.z;
  const int n0 = nt * 128, m0 = mt * 128;
  const int t = threadIdx.x;

  {
    const unsigned short* an = a_n + (size_t)b * ND;
    int p = t & 7;
    int x0 = (t >> 3) * 64;
#pragma unroll
    for (int j = 0; j < 64; j += 4) {
      ushort4 u;
      u.x = an[(x0 + j + 0 + p) & 1023];
      u.y = an[(x0 + j + 1 + p) & 1023];
      u.z = an[(x0 + j + 2 + p) & 1023];
      u.w = an[(x0 + j + 3 + p) & 1023];
      *(ushort4*)&copies[p][x0 + j] = u;
    }
  }

  const int ar = t >> 3;
  const int ac = (t & 7) * 4;
  float invn[4];
#pragma unroll
  for (int w = 0; w < 4; ++w)
    invn[w] = inv_norm[b * NS + m0 + ar + 32 * w];

  const int lane = t & 63;
  const int wv = t >> 6;
  const int wm = wv >> 1, wn = wv & 1;
  const int q = lane >> 4, l16 = lane & 15;

  f32x4 acc[4][4];
#pragma unroll
  for (int i = 0; i < 4; ++i)
#pragma unroll
    for (int j = 0; j < 4; ++j)
      acc[i][j] = (f32x4){0.f, 0.f, 0.f, 0.f};

  const float* embB = emb + ((size_t)b * NS + m0) * ND;

  for (int k0 = 0; k0 < ND; k0 += 32) {
    __syncthreads();
#pragma unroll
    for (int w = 0; w < 4; ++w) {
      int r = ar + 32 * w;
      float4 v = *(const float4*)(embB + (size_t)r * ND + k0 + ac);
      float in = invn[w];
      ushort4 u;
      u.x = f2bf(v.x * in); u.y = f2bf(v.y * in);
      u.z = f2bf(v.z * in); u.w = f2bf(v.w * in);
      *(ushort4*)&Atile[r][ac] = u;
    }
    __syncthreads();

    bf16x8 af[4], bfr[4];
#pragma unroll
    for (int r = 0; r < 4; ++r) {
      int m = wm * 64 + r * 16 + l16;
      af[r] = *(const bf16x8*)&Atile[m][q * 8];
    }
#pragma unroll
    for (int r = 0; r < 4; ++r) {
      int ng = n0 + wn * 64 + r * 16 + l16;
      int e0 = k0 + 8 * q - ng + 1024;
      int p = e0 & 7;
      bfr[r] = *(const bf16x8*)&copies[p][e0 - p];
    }
#pragma unroll
    for (int i = 0; i < 4; ++i)
#pragma unroll
      for (int j = 0; j < 4; ++j)
        acc[i][j] = __builtin_amdgcn_mfma_f32_16x16x32_bf16(af[i], bfr[j], acc[i][j], 0, 0, 0);
  }

  float* outB = out + ((size_t)b * NS + m0) * ND + n0;
#pragma unroll
  for (int i = 0; i < 4; ++i) {
#pragma unroll
    for (int rg = 0; rg < 4; ++rg) {
      int s = wm * 64 + i * 16 + q * 4 + rg;
      float* orow = outB + (size_t)s * ND + wn * 64 + l16;
#pragma unroll
      for (int j = 0; j < 4; ++j)
        orow[j * 16] = acc[i][j][rg];
    }
  }
}

extern "C" void kernel_launch(void* const* d_in, const int* in_sizes, int n_in,
                              void* d_out, int out_size, void* d_ws, size_t ws_size,
                              hipStream_t stream) {
  const float* emb = (const float*)d_in[0];
  const float* aspect = (const float*)d_in[1];
  float* out = (float*)d_out;

  const size_t need = 65536 + (size_t)NB * NS * ND * 2;  // a_n + eN(bf16)

  if (ws_size >= need) {
    unsigned short* a_n = (unsigned short*)d_ws;
    unsigned short* eN = (unsigned short*)((char*)d_ws + 65536);
    anorm_kernel<<<NB, 256, 0, stream>>>(aspect, a_n);
    enormbf_kernel<<<4096, 256, 0, stream>>>(emb, eN);
    // grid (b, mt, nt): nt- and mt-siblings differ by multiples of 8 in flat id
    // -> same XCD -> A-panel L2 reuse; XCD = b % 8.
    corr_gemm4_kernel<<<dim3(NB, 2, 4), 512, 0, stream>>>(eN, a_n, out);
  } else {
    float* inv_norm = (float*)d_ws;
    unsigned short* a_n = (unsigned short*)((char*)d_ws + 65536);
    enorm_kernel<<<4096, 256, 0, stream>>>(emb, inv_norm);
    anorm_kernel<<<NB, 256, 0, stream>>>(aspect, a_n);
    corr_gemm_kernel<<<dim3(8, 4, NB), 256, 0, stream>>>(emb, inv_norm, a_n, out);
  }
}

// Round 2
// 141.006 us; speedup vs baseline: 1.0243x; 1.0243x over previous
//
#include <hip/hip_runtime.h>
#include <hip/hip_bf16.h>

typedef __attribute__((ext_vector_type(8))) short bf16x8;
typedef __attribute__((ext_vector_type(4))) float f32x4;

#define NB 32
#define NS 512
#define ND 1024

__device__ __forceinline__ unsigned short f2bf(float f) {
  unsigned int u = __float_as_uint(f);
  u = (u + 0x7FFFu + ((u >> 16) & 1u)) >> 16;  // RNE
  return (unsigned short)u;
}

// ---------- normalized embeddings -> bf16; blocks 0..31 also do aspect ----------
__global__ __launch_bounds__(256)
void enormbf_fused_kernel(const float* __restrict__ emb,
                          unsigned short* __restrict__ eN,
                          const float* __restrict__ aspect,
                          unsigned short* __restrict__ a_n) {
  int wave = threadIdx.x >> 6, lane = threadIdx.x & 63;
  size_t row = (size_t)blockIdx.x * 4 + wave;  // 0..16383
  const float4* p = (const float4*)(emb + row * ND);
  float4 v[4];
  float s = 0.f;
#pragma unroll
  for (int j = 0; j < 4; ++j) {
    v[j] = p[lane + 64 * j];
    s += v[j].x * v[j].x + v[j].y * v[j].y + v[j].z * v[j].z + v[j].w * v[j].w;
  }
#pragma unroll
  for (int off = 32; off >= 1; off >>= 1) s += __shfl_xor(s, off);
  float inv = (s > 0.f) ? (1.f / sqrtf(s)) : 0.f;
  ushort4* o = (ushort4*)(eN + row * ND);
#pragma unroll
  for (int j = 0; j < 4; ++j) {
    ushort4 u;
    u.x = f2bf(v[j].x * inv); u.y = f2bf(v[j].y * inv);
    u.z = f2bf(v[j].z * inv); u.w = f2bf(v[j].w * inv);
    o[lane + 64 * j] = u;
  }

  if (blockIdx.x < NB) {  // fused anorm for batch b = blockIdx.x
    int b = blockIdx.x;
    int t = threadIdx.x;
    const float4* pa = (const float4*)(aspect + (size_t)b * ND);
    float4 va = pa[t];
    float sa = va.x * va.x + va.y * va.y + va.z * va.z + va.w * va.w;
#pragma unroll
    for (int off = 32; off >= 1; off >>= 1) sa += __shfl_down(sa, off);
    __shared__ float red[4];
    if ((t & 63) == 0) red[t >> 6] = sa;
    __syncthreads();
    float tot = red[0] + red[1] + red[2] + red[3];
    float inva = (tot > 0.f) ? (1.f / sqrtf(tot)) : 0.f;
    ushort4 u;
    u.x = f2bf(va.x * inva); u.y = f2bf(va.y * inva);
    u.z = f2bf(va.z * inva); u.w = f2bf(va.w * inva);
    ((ushort4*)(a_n + (size_t)b * ND))[t] = u;
  }
}

// ---------- GEMM v5: 256x256 tile, 8 waves, operand-pipelined phases ----------
// Fix for v4's serialization: phase P issues the ds_reads for phase P+1 and
// waits lgkmcnt(4) (drain older group only) -> LDS pipe runs UNDER the MFMA
// cluster instead of before it. 5 barriers/tile instead of 8.
// Ring-3 A slots: c0=read, c1=next (drained at ph1 vmcnt), c2=staging (kt+2).
__global__ __launch_bounds__(512, 2)
void corr_gemm5_kernel(const unsigned short* __restrict__ eN,
                       const unsigned short* __restrict__ a_n,
                       float* __restrict__ out) {
  __shared__ __align__(16) unsigned short Alds[3 * 16384];   // 3 x 256 x 64
  __shared__ __align__(16) unsigned short copies[8 * 1288];

  const int b = blockIdx.x, mt = blockIdx.y, nt = blockIdx.z;
  const int n0 = nt * 256, m0 = mt * 256;
  const int tid = threadIdx.x;

  const int lane = tid & 63, wv = tid >> 6;
  const int wm = wv >> 2, wn = wv & 3;      // 2x4 waves over 256x256 (128x64 each)
  const int q = lane >> 4, l16 = lane & 15;
  const int mx = l16 & 7;
  const int s00 = (q ^ mx) * 8;             // chunk q       (kk=0)
  const int s01 = ((4 + q) ^ mx) * 8;       // chunk 4+q     (kk=1)
  const int arow = (wm * 128 + l16) * 64;

  // B read base: addr = copies + pB*1287 + idx ; idx = kt*64 + kk*32 + 8q + 256 - n_local
  const int pB = (8 - mx) & 7;
  const unsigned short* Bp = copies + pB * 1287 + (256 + 8 * q - wn * 64 - l16);

  // A staging source (inverse chunk swizzle), linear LDS dst = tid*16 per issue block
  const unsigned short* gstage =
      eN + ((size_t)b * NS + m0 + (tid >> 3)) * ND + (size_t)(((tid & 7) ^ ((tid >> 3) & 7)) * 8);
  char* ldsAbase = (char*)Alds;

  // ---- prologue part 1: gather a_n window into regs (vmcnt ops, consumed below) ----
  unsigned short av[20];
  {
    const unsigned short* an = a_n + (size_t)b * ND;
    const int p = tid & 7;
    const int x0 = (tid >> 3) * 20;                 // 64 threads/copy x 20 = 1280
    const int base = (768 - n0 + p) & 1023;
#pragma unroll
    for (int j = 0; j < 20; ++j) av[j] = an[(base + x0 + j) & 1023];
  }

  // ---- prologue part 2: issue stages for tiles 0 and 1 (stay in flight) ----
#pragma unroll
  for (int j = 0; j < 4; ++j)
    __builtin_amdgcn_global_load_lds(
        (const __attribute__((address_space(1))) void*)(gstage + (size_t)j * 64 * ND),
        (__attribute__((address_space(3))) void*)(ldsAbase + (size_t)tid * 16 + j * 8192),
        16, 0, 0);
#pragma unroll
  for (int j = 0; j < 4; ++j)
    __builtin_amdgcn_global_load_lds(
        (const __attribute__((address_space(1))) void*)(gstage + (size_t)j * 64 * ND + 64),
        (__attribute__((address_space(3))) void*)(ldsAbase + 32768 + (size_t)tid * 16 + j * 8192),
        16, 0, 0);

  // ---- prologue part 3: write copies from regs (ds_write; waits only a_n loads,
  // which are OLDER than the stages -> compiler wait drains a_n, keeps stages) ----
  {
    const int p = tid & 7;
    const int x0 = (tid >> 3) * 20;
#pragma unroll
    for (int j = 0; j < 20; ++j) copies[p * 1288 + x0 + j] = av[j];
  }

  f32x4 acc[8][4];
#pragma unroll
  for (int i = 0; i < 8; ++i)
#pragma unroll
    for (int j = 0; j < 4; ++j)
      acc[i][j] = (f32x4){0.f, 0.f, 0.f, 0.f};

  asm volatile("s_waitcnt lgkmcnt(0)" ::: "memory");   // copies writes done (per-wave)
  __builtin_amdgcn_s_barrier();                        // copies visible to all
  asm volatile("s_waitcnt vmcnt(4)" ::: "memory");     // tile0 retired (per-wave)
  __builtin_amdgcn_s_barrier();                        // tile0 fully in LDS

  bf16x8 a0[4], a1[4], bfr[4][2];

#define ISSUE_A(DST, BASE, PHN)                                          \
  do {                                                                   \
    DST[0] = *(const bf16x8*)&(BASE)[arow + (PHN) * 2048 + s00];         \
    DST[1] = *(const bf16x8*)&(BASE)[arow + (PHN) * 2048 + s01];         \
    DST[2] = *(const bf16x8*)&(BASE)[arow + (PHN) * 2048 + 1024 + s00];  \
    DST[3] = *(const bf16x8*)&(BASE)[arow + (PHN) * 2048 + 1024 + s01];  \
  } while (0)

#define STAGE_PAIR(J0)                                                                   \
  do {                                                                                   \
    if (kt + 2 < 16) {                                                                   \
      const unsigned short* sg_ = gstage + (size_t)(kt + 2) * 64;                        \
      char* dl_ = ldsAbase + c2 * 32768 + (size_t)tid * 16;                              \
      __builtin_amdgcn_global_load_lds(                                                  \
          (const __attribute__((address_space(1))) void*)(sg_ + (size_t)(J0) * 64 * ND), \
          (__attribute__((address_space(3))) void*)(dl_ + (J0) * 8192), 16, 0, 0);       \
      __builtin_amdgcn_global_load_lds(                                                  \
          (const __attribute__((address_space(1))) void*)(sg_ + (size_t)((J0) + 1) * 64 * ND), \
          (__attribute__((address_space(3))) void*)(dl_ + ((J0) + 1) * 8192), 16, 0, 0); \
    }                                                                                    \
  } while (0)

#define MFMA_PH(PH, CS)                                                                       \
  do {                                                                                        \
    __builtin_amdgcn_s_setprio(1);                                                            \
    _Pragma("unroll")                                                                         \
    for (int n = 0; n < 4; ++n) {                                                             \
      acc[2*(PH)][n]   = __builtin_amdgcn_mfma_f32_16x16x32_bf16(CS[0], bfr[n][0], acc[2*(PH)][n],   0, 0, 0); \
      acc[2*(PH)][n]   = __builtin_amdgcn_mfma_f32_16x16x32_bf16(CS[1], bfr[n][1], acc[2*(PH)][n],   0, 0, 0); \
      acc[2*(PH)+1][n] = __builtin_amdgcn_mfma_f32_16x16x32_bf16(CS[2], bfr[n][0], acc[2*(PH)+1][n], 0, 0, 0); \
      acc[2*(PH)+1][n] = __builtin_amdgcn_mfma_f32_16x16x32_bf16(CS[3], bfr[n][1], acc[2*(PH)+1][n], 0, 0, 0); \
    }                                                                                         \
    __builtin_amdgcn_s_setprio(0);                                                            \
  } while (0)

  int c0 = 0, c1 = 1, c2 = 2;

  // prime phase-0 operands of tile 0
  ISSUE_A(a0, Alds, 0);

#pragma unroll 1
  for (int kt = 0; kt < 16; ++kt) {
    const unsigned short* At = Alds + c0 * 16384;
    const unsigned short* An = Alds + c1 * 16384;

    // ---- phase 0: consume a0 + B(kt); issue B, a1<-ph1; stage pair0 ----
    {
      const unsigned short* Bt = Bp + kt * 64;
#pragma unroll
      for (int n = 0; n < 4; ++n) {
        bfr[n][0] = *(const bf16x8*)(Bt - n * 16);
        bfr[n][1] = *(const bf16x8*)(Bt + 32 - n * 16);
      }
    }
    __builtin_amdgcn_sched_barrier(0);   // pin B-issue before a1-issue
    ISSUE_A(a1, At, 1);
    STAGE_PAIR(0);
    __builtin_amdgcn_sched_barrier(0);
    __builtin_amdgcn_s_barrier();
    asm volatile("s_waitcnt lgkmcnt(4)" ::: "memory");  // a0+B ready; a1 in flight
    __builtin_amdgcn_sched_barrier(0);
    MFMA_PH(0, a0);

    // ---- phase 1: consume a1; issue a0<-ph2; stage pair2; counted vmcnt ----
    ISSUE_A(a0, At, 2);
    STAGE_PAIR(2);
    if (kt < 14) {
      asm volatile("s_waitcnt vmcnt(4)" ::: "memory");  // c1 drained; c2's 4 in flight
    } else {
      asm volatile("s_waitcnt vmcnt(0)" ::: "memory");  // tail: drain remaining stages
    }
    __builtin_amdgcn_sched_barrier(0);
    __builtin_amdgcn_s_barrier();
    asm volatile("s_waitcnt lgkmcnt(4)" ::: "memory");
    __builtin_amdgcn_sched_barrier(0);
    MFMA_PH(1, a1);

    // ---- phase 2: consume a0; issue a1<-ph3 ----
    ISSUE_A(a1, At, 3);
    __builtin_amdgcn_sched_barrier(0);
    __builtin_amdgcn_s_barrier();   // also orders ph1's vmcnt before ph3's c1-reads
    asm volatile("s_waitcnt lgkmcnt(4)" ::: "memory");
    __builtin_amdgcn_sched_barrier(0);
    MFMA_PH(2, a0);

    // ---- phase 3: consume a1; issue a0<-An ph0 (next tile) ----
    if (kt < 15) {
      ISSUE_A(a0, An, 0);
      __builtin_amdgcn_sched_barrier(0);
      __builtin_amdgcn_s_barrier();
      asm volatile("s_waitcnt lgkmcnt(4)" ::: "memory");
    } else {
      __builtin_amdgcn_s_barrier();
      asm volatile("s_waitcnt lgkmcnt(0)" ::: "memory");
    }
    __builtin_amdgcn_sched_barrier(0);
    MFMA_PH(3, a1);
    __builtin_amdgcn_s_barrier();   // tile end: c0 safe to recycle as next c2

    int tmp = c0; c0 = c1; c1 = c2; c2 = tmp;
  }
#undef MFMA_PH
#undef STAGE_PAIR
#undef ISSUE_A

  // epilogue: C/D layout col=lane&15, row=(lane>>4)*4+reg
  float* outB = out + ((size_t)b * NS + m0) * ND + n0;
#pragma unroll
  for (int i = 0; i < 8; ++i) {
#pragma unroll
    for (int rg = 0; rg < 4; ++rg) {
      int r = wm * 128 + i * 16 + q * 4 + rg;
      float* orow = outB + (size_t)r * ND + wn * 64 + l16;
#pragma unroll
      for (int n = 0; n < 4; ++n)
        orow[n * 16] = acc[i][n][rg];
    }
  }
}

// ---------- fallback path (round-1 kernels) in case ws is small ----------
__global__ void anorm_kernel(const float* __restrict__ aspect,
                             unsigned short* __restrict__ a_n) {
  int b = blockIdx.x;
  int t = threadIdx.x;
  const float4* p = (const float4*)(aspect + (size_t)b * ND);
  float4 v = p[t];
  float s = v.x * v.x + v.y * v.y + v.z * v.z + v.w * v.w;
#pragma unroll
  for (int off = 32; off >= 1; off >>= 1) s += __shfl_down(s, off);
  __shared__ float red[4];
  if ((t & 63) == 0) red[t >> 6] = s;
  __syncthreads();
  float tot = red[0] + red[1] + red[2] + red[3];
  float inv = (tot > 0.f) ? (1.f / sqrtf(tot)) : 0.f;
  ushort4 u;
  u.x = f2bf(v.x * inv); u.y = f2bf(v.y * inv);
  u.z = f2bf(v.z * inv); u.w = f2bf(v.w * inv);
  ((ushort4*)(a_n + (size_t)b * ND))[t] = u;
}

__global__ void enorm_kernel(const float* __restrict__ emb,
                             float* __restrict__ inv_norm) {
  int wave = threadIdx.x >> 6;
  int lane = threadIdx.x & 63;
  int row = blockIdx.x * 4 + wave;
  const float4* p = (const float4*)(emb + (size_t)row * ND);
  float s = 0.f;
#pragma unroll
  for (int j = 0; j < 4; ++j) {
    float4 v = p[lane + 64 * j];
    s += v.x * v.x + v.y * v.y + v.z * v.z + v.w * v.w;
  }
#pragma unroll
  for (int off = 32; off >= 1; off >>= 1) s += __shfl_down(s, off);
  if (lane == 0) inv_norm[row] = (s > 0.f) ? (1.f / sqrtf(s)) : 0.f;
}

__global__ __launch_bounds__(256)
void corr_gemm_kernel(const float* __restrict__ emb,
                      const float* __restrict__ inv_norm,
                      const unsigned short* __restrict__ a_n,
                      float* __restrict__ out) {
  __shared__ unsigned short copies[8][2056];
  __shared__ unsigned short Atile[128][40];

  const int nt = blockIdx.x, mt = blockIdx.y, b = blockIdx.z;
  const int n0 = nt * 128, m0 = mt * 128;
  const int t = threadIdx.x;

  {
    const unsigned short* an = a_n + (size_t)b * ND;
    int p = t & 7;
    int x0 = (t >> 3) * 64;
#pragma unroll
    for (int j = 0; j < 64; j += 4) {
      ushort4 u;
      u.x = an[(x0 + j + 0 + p) & 1023];
      u.y = an[(x0 + j + 1 + p) & 1023];
      u.z = an[(x0 + j + 2 + p) & 1023];
      u.w = an[(x0 + j + 3 + p) & 1023];
      *(ushort4*)&copies[p][x0 + j] = u;
    }
  }

  const int ar = t >> 3;
  const int ac = (t & 7) * 4;
  float invn[4];
#pragma unroll
  for (int w = 0; w < 4; ++w)
    invn[w] = inv_norm[b * NS + m0 + ar + 32 * w];

  const int lane = t & 63;
  const int wv = t >> 6;
  const int wm = wv >> 1, wn = wv & 1;
  const int q = lane >> 4, l16 = lane & 15;

  f32x4 acc[4][4];
#pragma unroll
  for (int i = 0; i < 4; ++i)
#pragma unroll
    for (int j = 0; j < 4; ++j)
      acc[i][j] = (f32x4){0.f, 0.f, 0.f, 0.f};

  const float* embB = emb + ((size_t)b * NS + m0) * ND;

  for (int k0 = 0; k0 < ND; k0 += 32) {
    __syncthreads();
#pragma unroll
    for (int w = 0; w < 4; ++w) {
      int r = ar + 32 * w;
      float4 v = *(const float4*)(embB + (size_t)r * ND + k0 + ac);
      float in = invn[w];
      ushort4 u;
      u.x = f2bf(v.x * in); u.y = f2bf(v.y * in);
      u.z = f2bf(v.z * in); u.w = f2bf(v.w * in);
      *(ushort4*)&Atile[r][ac] = u;
    }
    __syncthreads();

    bf16x8 af[4], bfr[4];
#pragma unroll
    for (int r = 0; r < 4; ++r) {
      int m = wm * 64 + r * 16 + l16;
      af[r] = *(const bf16x8*)&Atile[m][q * 8];
    }
#pragma unroll
    for (int r = 0; r < 4; ++r) {
      int ng = n0 + wn * 64 + r * 16 + l16;
      int e0 = k0 + 8 * q - ng + 1024;
      int p = e0 & 7;
      bfr[r] = *(const bf16x8*)&copies[p][e0 - p];
    }
#pragma unroll
    for (int i = 0; i < 4; ++i)
#pragma unroll
      for (int j = 0; j < 4; ++j)
        acc[i][j] = __builtin_amdgcn_mfma_f32_16x16x32_bf16(af[i], bfr[j], acc[i][j], 0, 0, 0);
  }

  float* outB = out + ((size_t)b * NS + m0) * ND + n0;
#pragma unroll
  for (int i = 0; i < 4; ++i) {
#pragma unroll
    for (int rg = 0; rg < 4; ++rg) {
      int s = wm * 64 + i * 16 + q * 4 + rg;
      float* orow = outB + (size_t)s * ND + wn * 64 + l16;
#pragma unroll
      for (int j = 0; j < 4; ++j)
        orow[j * 16] = acc[i][j][rg];
    }
  }
}

extern "C" void kernel_launch(void* const* d_in, const int* in_sizes, int n_in,
                              void* d_out, int out_size, void* d_ws, size_t ws_size,
                              hipStream_t stream) {
  const float* emb = (const float*)d_in[0];
  const float* aspect = (const float*)d_in[1];
  float* out = (float*)d_out;

  const size_t need = 65536 + (size_t)NB * NS * ND * 2;  // a_n + eN(bf16)

  if (ws_size >= need) {
    unsigned short* a_n = (unsigned short*)d_ws;
    unsigned short* eN = (unsigned short*)((char*)d_ws + 65536);
    enormbf_fused_kernel<<<4096, 256, 0, stream>>>(emb, eN, aspect, a_n);
    // grid (b, mt, nt): all 8 tiles of a batch share XCD (= b % 8) -> A-panel L2 reuse
    corr_gemm5_kernel<<<dim3(NB, 2, 4), 512, 0, stream>>>(eN, a_n, out);
  } else {
    float* inv_norm = (float*)d_ws;
    unsigned short* a_n = (unsigned short*)((char*)d_ws + 65536);
    enorm_kernel<<<4096, 256, 0, stream>>>(emb, inv_norm);
    anorm_kernel<<<NB, 256, 0, stream>>>(aspect, a_n);
    corr_gemm_kernel<<<dim3(8, 4, NB), 256, 0, stream>>>(emb, inv_norm, a_n, out);
  }
}